// Round 13
// baseline (556.031 us; speedup 1.0000x reference)
//
#include <hip/hip_runtime.h>

// ---------------------------------------------------------------------------
// Pipeline:
//  k_prep : w2[64,32,3] -> w2t[3,32,64]; wfc[512,64] -> wB{h,m,l} bf16
//  kA     : h[v] = mean_j relu(conv3_j(vp[nb1[v,:]]))               [V]
//  kB     : h3[v] = (h[v-1], h[v], h[v+1], 0)                       [V,4]
//  kF     : FUSED kC+kD+kE per 32-vertex block (ph1..ph4)
//
// R16 change: ph4 de-spilled. R12 counters: WRITE=275MB vs 200MB mandatory
// (+75MB = scratch spills), VGPR_Count=96 vs ~150 live in ph4's two-row-set
// MFMA (12 frags + 2x acc[8]), VALUBusy 41% @ MfmaUtil 9%. The two-row-set
// B-reuse was proven NULL in R9 (B frags are L1/L2-hot) -- so drop it:
// ph4 now runs TWO sequential 16-row passes, each with 6 frag arrays (24
// VGPR) + acc[8] (32) + temps ~= 80 live. launch_bounds(256,4) caps 128
// VGPR (headroom, no spill) -> 4 blocks/CU. Verify: WRITE -> ~205MB.
// ---------------------------------------------------------------------------

typedef short bf16x8 __attribute__((ext_vector_type(8)));
typedef float f32x4 __attribute__((ext_vector_type(4)));

__device__ inline unsigned short f2bf(float x) {
    unsigned u = __float_as_uint(x);
    unsigned r = (u + 0x7FFFu + ((u >> 16) & 1u)) >> 16;
    return (unsigned short)r;
}
__device__ inline float bf2f(unsigned short b) {
    return __uint_as_float(((unsigned)b) << 16);
}

// k_prep: w2 transpose + wfc -> 3-way bf16 split in B-fragment order.
__global__ __launch_bounds__(256) void k_prep(const float* __restrict__ wfc,
                                              const float* __restrict__ w2,
                                              short* __restrict__ wBh,
                                              short* __restrict__ wBm,
                                              short* __restrict__ wBl,
                                              float* __restrict__ w2t) {
    int t = blockIdx.x * 256 + threadIdx.x;
    if (t < 32768) {
        int j = t & 7;
        int l = (t >> 3) & 63;
        int s = (t >> 9) & 1;
        int n = t >> 10;
        int col = n * 16 + (l & 15);
        int k = s * 32 + (l >> 4) * 8 + j;
        float v = wfc[col * 64 + k];
        unsigned short h = f2bf(v);
        float r1 = v - bf2f(h);
        unsigned short m = f2bf(r1);
        float r2 = r1 - bf2f(m);
        wBh[t] = (short)h;
        wBm[t] = (short)m;
        wBl[t] = (short)f2bf(r2);
    } else if (t < 32768 + 6144) {
        int i = t - 32768;
        int o = i / 96;
        int r = i - o * 96;
        int c = r / 3;
        int k = r - c * 3;
        w2t[(k * 32 + c) * 64 + o] = w2[i];
    }
}

// conv1 over neighbor axis: one 32-lane segment per vertex
__global__ __launch_bounds__(256) void kA(const float* __restrict__ vp,
                                          const int* __restrict__ nb1,
                                          const float* __restrict__ wv1,
                                          const float* __restrict__ bv1,
                                          float* __restrict__ h, int V) {
    int t = blockIdx.x * 256 + threadIdx.x;
    int v = t >> 5;
    int j = t & 31;
    if (v >= V) return;
    float g = vp[nb1[v * 32 + j]];
    float gm = __shfl_up(g, 1, 32);
    if (j == 0) gm = 0.0f;
    float gp = __shfl_down(g, 1, 32);
    if (j == 31) gp = 0.0f;
    float c = wv1[0] * gm + wv1[1] * g + wv1[2] * gp + bv1[0];
    c = fmaxf(c, 0.0f);
    #pragma unroll
    for (int off = 16; off; off >>= 1) c += __shfl_xor(c, off, 32);
    if (j == 0) h[v] = c * (1.0f / 32.0f);
}

// h3 builder: h3[v] = (h[v-1], h[v], h[v+1], 0) -- 1.6MB, L2-resident
__global__ __launch_bounds__(256) void kB(const float* __restrict__ h,
                                          float* __restrict__ h3, int V) {
    int v = blockIdx.x * 256 + threadIdx.x;
    if (v >= V) return;
    float hm = (v > 0) ? h[v - 1] : 0.0f;
    float h0 = h[v];
    float hp = (v + 1 < V) ? h[v + 1] : 0.0f;
    *(float4*)(h3 + (size_t)v * 4) = make_float4(hm, h0, hp, 0.0f);
}

// FUSED kC+kD+kE. One block = 32 vertices. V % 32 == 0.
__global__ __launch_bounds__(256, 4) void kF(const float* __restrict__ h3,
                                             const int* __restrict__ nb2,
                                             const float* __restrict__ w1,
                                             const float* __restrict__ b1,
                                             const float* __restrict__ wv2,
                                             const float* __restrict__ bv2,
                                             const float* __restrict__ w2t,
                                             const float* __restrict__ b2,
                                             const short* __restrict__ wBh,
                                             const short* __restrict__ wBm,
                                             const short* __restrict__ wBl,
                                             const float* __restrict__ bfc,
                                             float* __restrict__ out, int V) {
    __shared__ float h3s[34 * 32 * 4];   // 17408 B; ph3+ aliased as f2s[32][68]
    __shared__ float h2s[34 * 32];       // 4352 B, rows v0-1 .. v0+32
    __shared__ float redmax[4][16];
    __shared__ float redsum[4][16];
    float* f2s = h3s;                    // alias (dead after ph2; barrier-fenced)

    int t = threadIdx.x;
    int vbase = blockIdx.x * 32;

    // ---- ph1: gather h3[nb2[v,j]] for 34 halo rows ----
    for (int i = t; i < 34 * 32; i += 256) {
        int r = i >> 5;                  // tile row, vertex v = vbase-1+r
        int j = i & 31;
        int v = vbase - 1 + r;
        float4 val = make_float4(0.f, 0.f, 0.f, 0.f);
        if (v >= 0 && v < V) {
            int idx = nb2[(size_t)v * 32 + j];
            val = *(const float4*)(h3 + (size_t)idx * 4);
        }
        *(float4*)(h3s + i * 4) = val;
    }
    __syncthreads();

    // ---- ph2: h2[r][c] = mean_j relu(conv3_j(f1_synth)) ----
    for (int i = t; i < 34 * 32; i += 256) {
        int r = i >> 5;
        int c = i & 31;
        int v = vbase - 1 + r;
        float res = 0.0f;
        if (v >= 0 && v < V) {
            float u0 = w1[c * 3 + 0], u1 = w1[c * 3 + 1], u2 = w1[c * 3 + 2];
            float bc = b1[c];
            float w0 = wv2[0], w1_ = wv2[1], w2_ = wv2[2], b = bv2[0];
            const float* base = h3s + r * 32 * 4;
            float4 hh = *(const float4*)(base);
            float xprev = 0.0f;
            float xcur = fmaf(hh.x, u0, fmaf(hh.y, u1, fmaf(hh.z, u2, bc)));
            float s = 0.0f;
            #pragma unroll
            for (int j = 0; j < 32; ++j) {
                float xnext = 0.0f;
                if (j < 31) {
                    float4 hn = *(const float4*)(base + (j + 1) * 4);
                    xnext = fmaf(hn.x, u0, fmaf(hn.y, u1, fmaf(hn.z, u2, bc)));
                }
                float cv = fmaf(w0, xprev, fmaf(w1_, xcur, fmaf(w2_, xnext, b)));
                s += fmaxf(cv, 0.0f);
                xprev = xcur;
                xcur = xnext;
            }
            res = s * (1.0f / 32.0f);
        }
        h2s[r * 32 + c] = res;
    }
    __syncthreads();

    // ---- ph3: kD einsum from h2s -> f2s[32][68] (LDS) ----
    {
        int o = t & 63;
        int w = t >> 6;
        int vb = w * 8;
        float bo = b2[o];
        float acc[8];
        #pragma unroll
        for (int m = 0; m < 8; ++m) acc[m] = bo;

        #pragma unroll
        for (int c4 = 0; c4 < 8; ++c4) {
            float4 hv[10];
            #pragma unroll
            for (int r = 0; r < 10; ++r)
                hv[r] = *(const float4*)(h2s + (vb + r) * 32 + c4 * 4);
            #pragma unroll
            for (int k = 0; k < 3; ++k) {
                #pragma unroll
                for (int cc = 0; cc < 4; ++cc) {
                    int c = c4 * 4 + cc;
                    float wv = w2t[(k * 32 + c) * 64 + o];
                    #pragma unroll
                    for (int m = 0; m < 8; ++m) {
                        float hval = (cc == 0) ? hv[m + k].x :
                                     (cc == 1) ? hv[m + k].y :
                                     (cc == 2) ? hv[m + k].z : hv[m + k].w;
                        acc[m] = fmaf(hval, wv, acc[m]);
                    }
                }
            }
        }
        __syncthreads();   // h3s reads (ph2) done everywhere; safe to alias
        #pragma unroll
        for (int m = 0; m < 8; ++m)
            f2s[(vb + m) * 68 + o] = acc[m];
    }
    __syncthreads();

    // ---- ph4: kE MFMA fc + softmax, TWO 16-row passes (low reg pressure) --
    int w = t >> 6;          // wave 0..3
    int l = t & 63;          // lane
    int c16 = l & 15;
    int g = l >> 4;          // K-group / row-group
    const bf16x8* Bh = (const bf16x8*)wBh;
    const bf16x8* Bm = (const bf16x8*)wBm;
    const bf16x8* Bl = (const bf16x8*)wBl;

    for (int set = 0; set < 2; ++set) {
        // A fragments for this 16-row set, 3-way bf16 split
        bf16x8 ah0, am0, al0, ah1, am1, al1;
#define SPLIT(AH, AM, AL, idx, x) { \
        float xx = (x); \
        unsigned short h_ = f2bf(xx); \
        float r1_ = xx - bf2f(h_); \
        unsigned short m_ = f2bf(r1_); \
        float r2_ = r1_ - bf2f(m_); \
        AH[idx] = (short)h_; AM[idx] = (short)m_; AL[idx] = (short)f2bf(r2_); }
        {
            const float* rowp = f2s + (set * 16 + c16) * 68 + g * 8;
            float4 q0 = *(const float4*)(rowp);        // s=0, k=g*8..+3
            float4 q1 = *(const float4*)(rowp + 4);    // s=0, k=g*8+4..+7
            float4 q2 = *(const float4*)(rowp + 32);   // s=1
            float4 q3 = *(const float4*)(rowp + 36);
            SPLIT(ah0, am0, al0, 0, q0.x) SPLIT(ah0, am0, al0, 1, q0.y)
            SPLIT(ah0, am0, al0, 2, q0.z) SPLIT(ah0, am0, al0, 3, q0.w)
            SPLIT(ah0, am0, al0, 4, q1.x) SPLIT(ah0, am0, al0, 5, q1.y)
            SPLIT(ah0, am0, al0, 6, q1.z) SPLIT(ah0, am0, al0, 7, q1.w)
            SPLIT(ah1, am1, al1, 0, q2.x) SPLIT(ah1, am1, al1, 1, q2.y)
            SPLIT(ah1, am1, al1, 2, q2.z) SPLIT(ah1, am1, al1, 3, q2.w)
            SPLIT(ah1, am1, al1, 4, q3.x) SPLIT(ah1, am1, al1, 5, q3.y)
            SPLIT(ah1, am1, al1, 6, q3.z) SPLIT(ah1, am1, al1, 7, q3.w)
        }
#undef SPLIT

        f32x4 acc[8];
        #pragma unroll
        for (int n8 = 0; n8 < 8; ++n8) {
            int n = w * 8 + n8;
            bf16x8 bh0 = Bh[(n * 2 + 0) * 64 + l];
            bf16x8 bm0 = Bm[(n * 2 + 0) * 64 + l];
            bf16x8 bl0 = Bl[(n * 2 + 0) * 64 + l];
            bf16x8 bh1 = Bh[(n * 2 + 1) * 64 + l];
            bf16x8 bm1 = Bm[(n * 2 + 1) * 64 + l];
            bf16x8 bl1 = Bl[(n * 2 + 1) * 64 + l];
            float bn = bfc[n * 16 + c16];
            f32x4 c = {0.f, 0.f, 0.f, 0.f};
            c = __builtin_amdgcn_mfma_f32_16x16x32_bf16(ah0, bh0, c, 0, 0, 0);
            c = __builtin_amdgcn_mfma_f32_16x16x32_bf16(ah0, bm0, c, 0, 0, 0);
            c = __builtin_amdgcn_mfma_f32_16x16x32_bf16(am0, bh0, c, 0, 0, 0);
            c = __builtin_amdgcn_mfma_f32_16x16x32_bf16(ah0, bl0, c, 0, 0, 0);
            c = __builtin_amdgcn_mfma_f32_16x16x32_bf16(am0, bm0, c, 0, 0, 0);
            c = __builtin_amdgcn_mfma_f32_16x16x32_bf16(al0, bh0, c, 0, 0, 0);
            c = __builtin_amdgcn_mfma_f32_16x16x32_bf16(ah1, bh1, c, 0, 0, 0);
            c = __builtin_amdgcn_mfma_f32_16x16x32_bf16(ah1, bm1, c, 0, 0, 0);
            c = __builtin_amdgcn_mfma_f32_16x16x32_bf16(am1, bh1, c, 0, 0, 0);
            c = __builtin_amdgcn_mfma_f32_16x16x32_bf16(ah1, bl1, c, 0, 0, 0);
            c = __builtin_amdgcn_mfma_f32_16x16x32_bf16(am1, bm1, c, 0, 0, 0);
            c = __builtin_amdgcn_mfma_f32_16x16x32_bf16(al1, bh1, c, 0, 0, 0);
            c.x += bn; c.y += bn; c.z += bn; c.w += bn;
            acc[n8] = c;
        }

        // softmax for rows set*16 + g*4 + j
        float m0 = -1e30f, m1 = -1e30f, m2 = -1e30f, m3 = -1e30f;
        #pragma unroll
        for (int n8 = 0; n8 < 8; ++n8) {
            m0 = fmaxf(m0, acc[n8].x); m1 = fmaxf(m1, acc[n8].y);
            m2 = fmaxf(m2, acc[n8].z); m3 = fmaxf(m3, acc[n8].w);
        }
        #pragma unroll
        for (int off = 8; off; off >>= 1) {
            m0 = fmaxf(m0, __shfl_xor(m0, off));
            m1 = fmaxf(m1, __shfl_xor(m1, off));
            m2 = fmaxf(m2, __shfl_xor(m2, off));
            m3 = fmaxf(m3, __shfl_xor(m3, off));
        }
        if (c16 == 0) {
            redmax[w][g * 4 + 0] = m0;  redmax[w][g * 4 + 1] = m1;
            redmax[w][g * 4 + 2] = m2;  redmax[w][g * 4 + 3] = m3;
        }
        __syncthreads();
#define GMAX(r) fmaxf(fmaxf(redmax[0][r], redmax[1][r]), \
                      fmaxf(redmax[2][r], redmax[3][r]))
        float g0 = GMAX(g * 4 + 0), g1 = GMAX(g * 4 + 1);
        float g2 = GMAX(g * 4 + 2), g3 = GMAX(g * 4 + 3);
#undef GMAX

        float s0 = 0.f, s1 = 0.f, s2 = 0.f, s3 = 0.f;
        #pragma unroll
        for (int n8 = 0; n8 < 8; ++n8) {
            acc[n8].x = __expf(acc[n8].x - g0); s0 += acc[n8].x;
            acc[n8].y = __expf(acc[n8].y - g1); s1 += acc[n8].y;
            acc[n8].z = __expf(acc[n8].z - g2); s2 += acc[n8].z;
            acc[n8].w = __expf(acc[n8].w - g3); s3 += acc[n8].w;
        }
        #pragma unroll
        for (int off = 8; off; off >>= 1) {
            s0 += __shfl_xor(s0, off); s1 += __shfl_xor(s1, off);
            s2 += __shfl_xor(s2, off); s3 += __shfl_xor(s3, off);
        }
        if (c16 == 0) {
            redsum[w][g * 4 + 0] = s0;  redsum[w][g * 4 + 1] = s1;
            redsum[w][g * 4 + 2] = s2;  redsum[w][g * 4 + 3] = s3;
        }
        __syncthreads();
#define GSUM(r) (redsum[0][r] + redsum[1][r] + redsum[2][r] + redsum[3][r])
        float i0 = 1.0f / GSUM(g * 4 + 0), i1 = 1.0f / GSUM(g * 4 + 1);
        float i2 = 1.0f / GSUM(g * 4 + 2), i3 = 1.0f / GSUM(g * 4 + 3);
#undef GSUM

        #pragma unroll
        for (int n8 = 0; n8 < 8; ++n8) {
            int n = w * 8 + n8;
            float* op = out + (size_t)(vbase + set * 16 + g * 4) * 512 + n * 16 + c16;
            __builtin_nontemporal_store(acc[n8].x * i0, op);
            __builtin_nontemporal_store(acc[n8].y * i1, op + 512);
            __builtin_nontemporal_store(acc[n8].z * i2, op + 1024);
            __builtin_nontemporal_store(acc[n8].w * i3, op + 1536);
        }
        __syncthreads();   // redmax/redsum reused next set
    }
}

extern "C" void kernel_launch(void* const* d_in, const int* in_sizes, int n_in,
                              void* d_out, int out_size, void* d_ws, size_t ws_size,
                              hipStream_t stream) {
    (void)n_in; (void)out_size; (void)ws_size;
    const float* vp  = (const float*)d_in[0];
    const int*   nb1 = (const int*)d_in[1];
    const int*   nb2 = (const int*)d_in[2];
    const float* wv1 = (const float*)d_in[3];
    const float* bv1 = (const float*)d_in[4];
    const float* w1  = (const float*)d_in[5];
    const float* b1  = (const float*)d_in[6];
    const float* wv2 = (const float*)d_in[7];
    const float* bv2 = (const float*)d_in[8];
    const float* w2  = (const float*)d_in[9];
    const float* b2  = (const float*)d_in[10];
    const float* wfc = (const float*)d_in[11];
    const float* bfc = (const float*)d_in[12];
    float* out = (float*)d_out;
    const int V = in_sizes[0];

    float* ws = (float*)d_ws;
    size_t off = 0;
    float* h    = ws + off; off += (size_t)V;
    float* h3   = ws + off; off += (size_t)V * 4;   // 16B aligned
    float* w2t  = ws + off; off += 3 * 32 * 64;
    short* wBh  = (short*)(ws + off); off += 32768 / 2;   // 32768 shorts
    short* wBm  = (short*)(ws + off); off += 32768 / 2;
    short* wBl  = (short*)(ws + off); off += 32768 / 2;

    k_prep<<<(32768 + 6144 + 255) / 256, 256, 0, stream>>>(wfc, w2, wBh, wBm, wBl, w2t);
    kA<<<(V * 32 + 255) / 256, 256, 0, stream>>>(vp, nb1, wv1, bv1, h, V);
    kB<<<(V + 255) / 256, 256, 0, stream>>>(h, h3, V);
    kF<<<V / 32, 256, 0, stream>>>(h3, nb2, w1, b1, wv2, bv2, w2t, b2,
                                   wBh, wBm, wBl, bfc, out, V);
}

// Round 14
// 464.491 us; speedup vs baseline: 1.1971x; 1.1971x over previous
//
#include <hip/hip_runtime.h>

// ---------------------------------------------------------------------------
// Pipeline:
//  k_prep : w2[64,32,3] -> w2t[3,32,64]; wfc[512,64] -> wB{h,m,l} bf16
//  kA     : h[v] = mean_j relu(conv3_j(vp[nb1[v,:]]))               [V]
//  kB     : h3[v] = (h[v-1], h[v], h[v+1], 0)                       [V,4]
//  kF     : FUSED kC+kD+kE per 32-vertex block (ph1..ph4)
//
// R17 = R16's two-pass ph4 with BARE __launch_bounds__(256).
// R16 post-mortem: (256,4) made the compiler TARGET 8 waves/EU and shrink
// the budget to 64 VGPR (< ~80 live even in the two-pass form) -> 1.1GB of
// scratch spill traffic (FETCH 572MB, WRITE 773MB), 353us. The second
// launch_bounds arg is an occupancy target that can push allocation BELOW
// live state -- never combine with a register-hungry body unchecked.
// Under bare bounds the compiler picks ~96 VGPR (R12 measured); two-pass
// ph4 live state ~80 fits -> zero spill (R12's one-pass 150-live did not).
// Verify: WRITE -> ~205MB, FETCH -> ~14MB, VGPR_Count -> ~96.
// ---------------------------------------------------------------------------

typedef short bf16x8 __attribute__((ext_vector_type(8)));
typedef float f32x4 __attribute__((ext_vector_type(4)));

__device__ inline unsigned short f2bf(float x) {
    unsigned u = __float_as_uint(x);
    unsigned r = (u + 0x7FFFu + ((u >> 16) & 1u)) >> 16;
    return (unsigned short)r;
}
__device__ inline float bf2f(unsigned short b) {
    return __uint_as_float(((unsigned)b) << 16);
}

// k_prep: w2 transpose + wfc -> 3-way bf16 split in B-fragment order.
__global__ __launch_bounds__(256) void k_prep(const float* __restrict__ wfc,
                                              const float* __restrict__ w2,
                                              short* __restrict__ wBh,
                                              short* __restrict__ wBm,
                                              short* __restrict__ wBl,
                                              float* __restrict__ w2t) {
    int t = blockIdx.x * 256 + threadIdx.x;
    if (t < 32768) {
        int j = t & 7;
        int l = (t >> 3) & 63;
        int s = (t >> 9) & 1;
        int n = t >> 10;
        int col = n * 16 + (l & 15);
        int k = s * 32 + (l >> 4) * 8 + j;
        float v = wfc[col * 64 + k];
        unsigned short h = f2bf(v);
        float r1 = v - bf2f(h);
        unsigned short m = f2bf(r1);
        float r2 = r1 - bf2f(m);
        wBh[t] = (short)h;
        wBm[t] = (short)m;
        wBl[t] = (short)f2bf(r2);
    } else if (t < 32768 + 6144) {
        int i = t - 32768;
        int o = i / 96;
        int r = i - o * 96;
        int c = r / 3;
        int k = r - c * 3;
        w2t[(k * 32 + c) * 64 + o] = w2[i];
    }
}

// conv1 over neighbor axis: one 32-lane segment per vertex
__global__ __launch_bounds__(256) void kA(const float* __restrict__ vp,
                                          const int* __restrict__ nb1,
                                          const float* __restrict__ wv1,
                                          const float* __restrict__ bv1,
                                          float* __restrict__ h, int V) {
    int t = blockIdx.x * 256 + threadIdx.x;
    int v = t >> 5;
    int j = t & 31;
    if (v >= V) return;
    float g = vp[nb1[v * 32 + j]];
    float gm = __shfl_up(g, 1, 32);
    if (j == 0) gm = 0.0f;
    float gp = __shfl_down(g, 1, 32);
    if (j == 31) gp = 0.0f;
    float c = wv1[0] * gm + wv1[1] * g + wv1[2] * gp + bv1[0];
    c = fmaxf(c, 0.0f);
    #pragma unroll
    for (int off = 16; off; off >>= 1) c += __shfl_xor(c, off, 32);
    if (j == 0) h[v] = c * (1.0f / 32.0f);
}

// h3 builder: h3[v] = (h[v-1], h[v], h[v+1], 0) -- 1.6MB, L2-resident
__global__ __launch_bounds__(256) void kB(const float* __restrict__ h,
                                          float* __restrict__ h3, int V) {
    int v = blockIdx.x * 256 + threadIdx.x;
    if (v >= V) return;
    float hm = (v > 0) ? h[v - 1] : 0.0f;
    float h0 = h[v];
    float hp = (v + 1 < V) ? h[v + 1] : 0.0f;
    *(float4*)(h3 + (size_t)v * 4) = make_float4(hm, h0, hp, 0.0f);
}

// FUSED kC+kD+kE. One block = 32 vertices. V % 32 == 0.
__global__ __launch_bounds__(256) void kF(const float* __restrict__ h3,
                                          const int* __restrict__ nb2,
                                          const float* __restrict__ w1,
                                          const float* __restrict__ b1,
                                          const float* __restrict__ wv2,
                                          const float* __restrict__ bv2,
                                          const float* __restrict__ w2t,
                                          const float* __restrict__ b2,
                                          const short* __restrict__ wBh,
                                          const short* __restrict__ wBm,
                                          const short* __restrict__ wBl,
                                          const float* __restrict__ bfc,
                                          float* __restrict__ out, int V) {
    __shared__ float h3s[34 * 32 * 4];   // 17408 B; ph3+ aliased as f2s[32][68]
    __shared__ float h2s[34 * 32];       // 4352 B, rows v0-1 .. v0+32
    __shared__ float redmax[4][16];
    __shared__ float redsum[4][16];
    float* f2s = h3s;                    // alias (dead after ph2; barrier-fenced)

    int t = threadIdx.x;
    int vbase = blockIdx.x * 32;

    // ---- ph1: gather h3[nb2[v,j]] for 34 halo rows ----
    for (int i = t; i < 34 * 32; i += 256) {
        int r = i >> 5;                  // tile row, vertex v = vbase-1+r
        int j = i & 31;
        int v = vbase - 1 + r;
        float4 val = make_float4(0.f, 0.f, 0.f, 0.f);
        if (v >= 0 && v < V) {
            int idx = nb2[(size_t)v * 32 + j];
            val = *(const float4*)(h3 + (size_t)idx * 4);
        }
        *(float4*)(h3s + i * 4) = val;
    }
    __syncthreads();

    // ---- ph2: h2[r][c] = mean_j relu(conv3_j(f1_synth)) ----
    for (int i = t; i < 34 * 32; i += 256) {
        int r = i >> 5;
        int c = i & 31;
        int v = vbase - 1 + r;
        float res = 0.0f;
        if (v >= 0 && v < V) {
            float u0 = w1[c * 3 + 0], u1 = w1[c * 3 + 1], u2 = w1[c * 3 + 2];
            float bc = b1[c];
            float w0 = wv2[0], w1_ = wv2[1], w2_ = wv2[2], b = bv2[0];
            const float* base = h3s + r * 32 * 4;
            float4 hh = *(const float4*)(base);
            float xprev = 0.0f;
            float xcur = fmaf(hh.x, u0, fmaf(hh.y, u1, fmaf(hh.z, u2, bc)));
            float s = 0.0f;
            #pragma unroll
            for (int j = 0; j < 32; ++j) {
                float xnext = 0.0f;
                if (j < 31) {
                    float4 hn = *(const float4*)(base + (j + 1) * 4);
                    xnext = fmaf(hn.x, u0, fmaf(hn.y, u1, fmaf(hn.z, u2, bc)));
                }
                float cv = fmaf(w0, xprev, fmaf(w1_, xcur, fmaf(w2_, xnext, b)));
                s += fmaxf(cv, 0.0f);
                xprev = xcur;
                xcur = xnext;
            }
            res = s * (1.0f / 32.0f);
        }
        h2s[r * 32 + c] = res;
    }
    __syncthreads();

    // ---- ph3: kD einsum from h2s -> f2s[32][68] (LDS) ----
    {
        int o = t & 63;
        int w = t >> 6;
        int vb = w * 8;
        float bo = b2[o];
        float acc[8];
        #pragma unroll
        for (int m = 0; m < 8; ++m) acc[m] = bo;

        #pragma unroll
        for (int c4 = 0; c4 < 8; ++c4) {
            float4 hv[10];
            #pragma unroll
            for (int r = 0; r < 10; ++r)
                hv[r] = *(const float4*)(h2s + (vb + r) * 32 + c4 * 4);
            #pragma unroll
            for (int k = 0; k < 3; ++k) {
                #pragma unroll
                for (int cc = 0; cc < 4; ++cc) {
                    int c = c4 * 4 + cc;
                    float wv = w2t[(k * 32 + c) * 64 + o];
                    #pragma unroll
                    for (int m = 0; m < 8; ++m) {
                        float hval = (cc == 0) ? hv[m + k].x :
                                     (cc == 1) ? hv[m + k].y :
                                     (cc == 2) ? hv[m + k].z : hv[m + k].w;
                        acc[m] = fmaf(hval, wv, acc[m]);
                    }
                }
            }
        }
        __syncthreads();   // h3s reads (ph2) done everywhere; safe to alias
        #pragma unroll
        for (int m = 0; m < 8; ++m)
            f2s[(vb + m) * 68 + o] = acc[m];
    }
    __syncthreads();

    // ---- ph4: kE MFMA fc + softmax, TWO 16-row passes (low reg pressure) --
    int w = t >> 6;          // wave 0..3
    int l = t & 63;          // lane
    int c16 = l & 15;
    int g = l >> 4;          // K-group / row-group
    const bf16x8* Bh = (const bf16x8*)wBh;
    const bf16x8* Bm = (const bf16x8*)wBm;
    const bf16x8* Bl = (const bf16x8*)wBl;

    for (int set = 0; set < 2; ++set) {
        // A fragments for this 16-row set, 3-way bf16 split
        bf16x8 ah0, am0, al0, ah1, am1, al1;
#define SPLIT(AH, AM, AL, idx, x) { \
        float xx = (x); \
        unsigned short h_ = f2bf(xx); \
        float r1_ = xx - bf2f(h_); \
        unsigned short m_ = f2bf(r1_); \
        float r2_ = r1_ - bf2f(m_); \
        AH[idx] = (short)h_; AM[idx] = (short)m_; AL[idx] = (short)f2bf(r2_); }
        {
            const float* rowp = f2s + (set * 16 + c16) * 68 + g * 8;
            float4 q0 = *(const float4*)(rowp);        // s=0, k=g*8..+3
            float4 q1 = *(const float4*)(rowp + 4);    // s=0, k=g*8+4..+7
            float4 q2 = *(const float4*)(rowp + 32);   // s=1
            float4 q3 = *(const float4*)(rowp + 36);
            SPLIT(ah0, am0, al0, 0, q0.x) SPLIT(ah0, am0, al0, 1, q0.y)
            SPLIT(ah0, am0, al0, 2, q0.z) SPLIT(ah0, am0, al0, 3, q0.w)
            SPLIT(ah0, am0, al0, 4, q1.x) SPLIT(ah0, am0, al0, 5, q1.y)
            SPLIT(ah0, am0, al0, 6, q1.z) SPLIT(ah0, am0, al0, 7, q1.w)
            SPLIT(ah1, am1, al1, 0, q2.x) SPLIT(ah1, am1, al1, 1, q2.y)
            SPLIT(ah1, am1, al1, 2, q2.z) SPLIT(ah1, am1, al1, 3, q2.w)
            SPLIT(ah1, am1, al1, 4, q3.x) SPLIT(ah1, am1, al1, 5, q3.y)
            SPLIT(ah1, am1, al1, 6, q3.z) SPLIT(ah1, am1, al1, 7, q3.w)
        }
#undef SPLIT

        f32x4 acc[8];
        #pragma unroll
        for (int n8 = 0; n8 < 8; ++n8) {
            int n = w * 8 + n8;
            bf16x8 bh0 = Bh[(n * 2 + 0) * 64 + l];
            bf16x8 bm0 = Bm[(n * 2 + 0) * 64 + l];
            bf16x8 bl0 = Bl[(n * 2 + 0) * 64 + l];
            bf16x8 bh1 = Bh[(n * 2 + 1) * 64 + l];
            bf16x8 bm1 = Bm[(n * 2 + 1) * 64 + l];
            bf16x8 bl1 = Bl[(n * 2 + 1) * 64 + l];
            float bn = bfc[n * 16 + c16];
            f32x4 c = {0.f, 0.f, 0.f, 0.f};
            c = __builtin_amdgcn_mfma_f32_16x16x32_bf16(ah0, bh0, c, 0, 0, 0);
            c = __builtin_amdgcn_mfma_f32_16x16x32_bf16(ah0, bm0, c, 0, 0, 0);
            c = __builtin_amdgcn_mfma_f32_16x16x32_bf16(am0, bh0, c, 0, 0, 0);
            c = __builtin_amdgcn_mfma_f32_16x16x32_bf16(ah0, bl0, c, 0, 0, 0);
            c = __builtin_amdgcn_mfma_f32_16x16x32_bf16(am0, bm0, c, 0, 0, 0);
            c = __builtin_amdgcn_mfma_f32_16x16x32_bf16(al0, bh0, c, 0, 0, 0);
            c = __builtin_amdgcn_mfma_f32_16x16x32_bf16(ah1, bh1, c, 0, 0, 0);
            c = __builtin_amdgcn_mfma_f32_16x16x32_bf16(ah1, bm1, c, 0, 0, 0);
            c = __builtin_amdgcn_mfma_f32_16x16x32_bf16(am1, bh1, c, 0, 0, 0);
            c = __builtin_amdgcn_mfma_f32_16x16x32_bf16(ah1, bl1, c, 0, 0, 0);
            c = __builtin_amdgcn_mfma_f32_16x16x32_bf16(am1, bm1, c, 0, 0, 0);
            c = __builtin_amdgcn_mfma_f32_16x16x32_bf16(al1, bh1, c, 0, 0, 0);
            c.x += bn; c.y += bn; c.z += bn; c.w += bn;
            acc[n8] = c;
        }

        // softmax for rows set*16 + g*4 + j
        float m0 = -1e30f, m1 = -1e30f, m2 = -1e30f, m3 = -1e30f;
        #pragma unroll
        for (int n8 = 0; n8 < 8; ++n8) {
            m0 = fmaxf(m0, acc[n8].x); m1 = fmaxf(m1, acc[n8].y);
            m2 = fmaxf(m2, acc[n8].z); m3 = fmaxf(m3, acc[n8].w);
        }
        #pragma unroll
        for (int off = 8; off; off >>= 1) {
            m0 = fmaxf(m0, __shfl_xor(m0, off));
            m1 = fmaxf(m1, __shfl_xor(m1, off));
            m2 = fmaxf(m2, __shfl_xor(m2, off));
            m3 = fmaxf(m3, __shfl_xor(m3, off));
        }
        if (c16 == 0) {
            redmax[w][g * 4 + 0] = m0;  redmax[w][g * 4 + 1] = m1;
            redmax[w][g * 4 + 2] = m2;  redmax[w][g * 4 + 3] = m3;
        }
        __syncthreads();
#define GMAX(r) fmaxf(fmaxf(redmax[0][r], redmax[1][r]), \
                      fmaxf(redmax[2][r], redmax[3][r]))
        float g0 = GMAX(g * 4 + 0), g1 = GMAX(g * 4 + 1);
        float g2 = GMAX(g * 4 + 2), g3 = GMAX(g * 4 + 3);
#undef GMAX

        float s0 = 0.f, s1 = 0.f, s2 = 0.f, s3 = 0.f;
        #pragma unroll
        for (int n8 = 0; n8 < 8; ++n8) {
            acc[n8].x = __expf(acc[n8].x - g0); s0 += acc[n8].x;
            acc[n8].y = __expf(acc[n8].y - g1); s1 += acc[n8].y;
            acc[n8].z = __expf(acc[n8].z - g2); s2 += acc[n8].z;
            acc[n8].w = __expf(acc[n8].w - g3); s3 += acc[n8].w;
        }
        #pragma unroll
        for (int off = 8; off; off >>= 1) {
            s0 += __shfl_xor(s0, off); s1 += __shfl_xor(s1, off);
            s2 += __shfl_xor(s2, off); s3 += __shfl_xor(s3, off);
        }
        if (c16 == 0) {
            redsum[w][g * 4 + 0] = s0;  redsum[w][g * 4 + 1] = s1;
            redsum[w][g * 4 + 2] = s2;  redsum[w][g * 4 + 3] = s3;
        }
        __syncthreads();
#define GSUM(r) (redsum[0][r] + redsum[1][r] + redsum[2][r] + redsum[3][r])
        float i0 = 1.0f / GSUM(g * 4 + 0), i1 = 1.0f / GSUM(g * 4 + 1);
        float i2 = 1.0f / GSUM(g * 4 + 2), i3 = 1.0f / GSUM(g * 4 + 3);
#undef GSUM

        #pragma unroll
        for (int n8 = 0; n8 < 8; ++n8) {
            int n = w * 8 + n8;
            float* op = out + (size_t)(vbase + set * 16 + g * 4) * 512 + n * 16 + c16;
            __builtin_nontemporal_store(acc[n8].x * i0, op);
            __builtin_nontemporal_store(acc[n8].y * i1, op + 512);
            __builtin_nontemporal_store(acc[n8].z * i2, op + 1024);
            __builtin_nontemporal_store(acc[n8].w * i3, op + 1536);
        }
        __syncthreads();   // redmax/redsum reused next set
    }
}

extern "C" void kernel_launch(void* const* d_in, const int* in_sizes, int n_in,
                              void* d_out, int out_size, void* d_ws, size_t ws_size,
                              hipStream_t stream) {
    (void)n_in; (void)out_size; (void)ws_size;
    const float* vp  = (const float*)d_in[0];
    const int*   nb1 = (const int*)d_in[1];
    const int*   nb2 = (const int*)d_in[2];
    const float* wv1 = (const float*)d_in[3];
    const float* bv1 = (const float*)d_in[4];
    const float* w1  = (const float*)d_in[5];
    const float* b1  = (const float*)d_in[6];
    const float* wv2 = (const float*)d_in[7];
    const float* bv2 = (const float*)d_in[8];
    const float* w2  = (const float*)d_in[9];
    const float* b2  = (const float*)d_in[10];
    const float* wfc = (const float*)d_in[11];
    const float* bfc = (const float*)d_in[12];
    float* out = (float*)d_out;
    const int V = in_sizes[0];

    float* ws = (float*)d_ws;
    size_t off = 0;
    float* h    = ws + off; off += (size_t)V;
    float* h3   = ws + off; off += (size_t)V * 4;   // 16B aligned
    float* w2t  = ws + off; off += 3 * 32 * 64;
    short* wBh  = (short*)(ws + off); off += 32768 / 2;   // 32768 shorts
    short* wBm  = (short*)(ws + off); off += 32768 / 2;
    short* wBl  = (short*)(ws + off); off += 32768 / 2;

    k_prep<<<(32768 + 6144 + 255) / 256, 256, 0, stream>>>(wfc, w2, wBh, wBm, wBl, w2t);
    kA<<<(V * 32 + 255) / 256, 256, 0, stream>>>(vp, nb1, wv1, bv1, h, V);
    kB<<<(V + 255) / 256, 256, 0, stream>>>(h, h3, V);
    kF<<<V / 32, 256, 0, stream>>>(h3, nb2, w1, b1, wv2, bv2, w2t, b2,
                                   wBh, wBm, wBl, bfc, out, V);
}

// Round 15
// 410.148 us; speedup vs baseline: 1.3557x; 1.1325x over previous
//
#include <hip/hip_runtime.h>

// ---------------------------------------------------------------------------
// Pipeline:
//  k_prep : w2[64,32,3] -> w2t[3,32,64]; wfc[512,64] -> wB{h,m,l} bf16
//  kA     : h[v] = mean_j relu(conv3_j(vp[nb1[v,:]]))               [V]
//  kB     : h3[v] = (h[v-1], h[v], h[v+1], 0)                       [V,4]
//  kF     : FUSED kC+kD+kE per 32-vertex block (ph1..ph4)
//
// R18 = R15's one-pass ph4 (the 386.5us best) + __launch_bounds__(256,3).
// RA ledger: R12 one-pass/bare -> 96 VGPR, +75MB spill, kF 178us (best).
//            R13 two-pass/(256,4) -> 64 VGPR cap < live, +573MB, 353us.
//            R14 two-pass/bare -> 156 VGPR (B-loads hoisted), 11% occ, 253us.
// Spill arithmetic: 75MB/(3125*256thr) ~= 94B/thr ~= 23 floats over R12's
// 96 budget -> one-pass live ~= 120. (256,3) caps at 512/3 ~= 170 VGPR:
// covers live with headroom (no spill) AND guarantees 3 waves/SIMD.
// Verify: VGPR ~168, WRITE -> ~205MB, FETCH ~14MB.
// ---------------------------------------------------------------------------

typedef short bf16x8 __attribute__((ext_vector_type(8)));
typedef float f32x4 __attribute__((ext_vector_type(4)));

__device__ inline unsigned short f2bf(float x) {
    unsigned u = __float_as_uint(x);
    unsigned r = (u + 0x7FFFu + ((u >> 16) & 1u)) >> 16;
    return (unsigned short)r;
}
__device__ inline float bf2f(unsigned short b) {
    return __uint_as_float(((unsigned)b) << 16);
}

// k_prep: w2 transpose + wfc -> 3-way bf16 split in B-fragment order.
__global__ __launch_bounds__(256) void k_prep(const float* __restrict__ wfc,
                                              const float* __restrict__ w2,
                                              short* __restrict__ wBh,
                                              short* __restrict__ wBm,
                                              short* __restrict__ wBl,
                                              float* __restrict__ w2t) {
    int t = blockIdx.x * 256 + threadIdx.x;
    if (t < 32768) {
        int j = t & 7;
        int l = (t >> 3) & 63;
        int s = (t >> 9) & 1;
        int n = t >> 10;
        int col = n * 16 + (l & 15);
        int k = s * 32 + (l >> 4) * 8 + j;
        float v = wfc[col * 64 + k];
        unsigned short h = f2bf(v);
        float r1 = v - bf2f(h);
        unsigned short m = f2bf(r1);
        float r2 = r1 - bf2f(m);
        wBh[t] = (short)h;
        wBm[t] = (short)m;
        wBl[t] = (short)f2bf(r2);
    } else if (t < 32768 + 6144) {
        int i = t - 32768;
        int o = i / 96;
        int r = i - o * 96;
        int c = r / 3;
        int k = r - c * 3;
        w2t[(k * 32 + c) * 64 + o] = w2[i];
    }
}

// conv1 over neighbor axis: one 32-lane segment per vertex
__global__ __launch_bounds__(256) void kA(const float* __restrict__ vp,
                                          const int* __restrict__ nb1,
                                          const float* __restrict__ wv1,
                                          const float* __restrict__ bv1,
                                          float* __restrict__ h, int V) {
    int t = blockIdx.x * 256 + threadIdx.x;
    int v = t >> 5;
    int j = t & 31;
    if (v >= V) return;
    float g = vp[nb1[v * 32 + j]];
    float gm = __shfl_up(g, 1, 32);
    if (j == 0) gm = 0.0f;
    float gp = __shfl_down(g, 1, 32);
    if (j == 31) gp = 0.0f;
    float c = wv1[0] * gm + wv1[1] * g + wv1[2] * gp + bv1[0];
    c = fmaxf(c, 0.0f);
    #pragma unroll
    for (int off = 16; off; off >>= 1) c += __shfl_xor(c, off, 32);
    if (j == 0) h[v] = c * (1.0f / 32.0f);
}

// h3 builder: h3[v] = (h[v-1], h[v], h[v+1], 0) -- 1.6MB, L2-resident
__global__ __launch_bounds__(256) void kB(const float* __restrict__ h,
                                          float* __restrict__ h3, int V) {
    int v = blockIdx.x * 256 + threadIdx.x;
    if (v >= V) return;
    float hm = (v > 0) ? h[v - 1] : 0.0f;
    float h0 = h[v];
    float hp = (v + 1 < V) ? h[v + 1] : 0.0f;
    *(float4*)(h3 + (size_t)v * 4) = make_float4(hm, h0, hp, 0.0f);
}

// FUSED kC+kD+kE. One block = 32 vertices. V % 32 == 0.
// (256,3): VGPR cap ~170 >= ~120 live -> no spill, 3 waves/SIMD.
__global__ __launch_bounds__(256, 3) void kF(const float* __restrict__ h3,
                                             const int* __restrict__ nb2,
                                             const float* __restrict__ w1,
                                             const float* __restrict__ b1,
                                             const float* __restrict__ wv2,
                                             const float* __restrict__ bv2,
                                             const float* __restrict__ w2t,
                                             const float* __restrict__ b2,
                                             const short* __restrict__ wBh,
                                             const short* __restrict__ wBm,
                                             const short* __restrict__ wBl,
                                             const float* __restrict__ bfc,
                                             float* __restrict__ out, int V) {
    __shared__ float h3s[34 * 32 * 4];   // 17408 B; ph3+ aliased as f2s[32][68]
    __shared__ float h2s[34 * 32];       // 4352 B, rows v0-1 .. v0+32
    __shared__ float redmax[4][32];
    __shared__ float redsum[4][32];
    float* f2s = h3s;                    // alias (dead after ph2; barrier-fenced)

    int t = threadIdx.x;
    int vbase = blockIdx.x * 32;

    // ---- ph1: gather h3[nb2[v,j]] for 34 halo rows ----
    for (int i = t; i < 34 * 32; i += 256) {
        int r = i >> 5;                  // tile row, vertex v = vbase-1+r
        int j = i & 31;
        int v = vbase - 1 + r;
        float4 val = make_float4(0.f, 0.f, 0.f, 0.f);
        if (v >= 0 && v < V) {
            int idx = nb2[(size_t)v * 32 + j];
            val = *(const float4*)(h3 + (size_t)idx * 4);
        }
        *(float4*)(h3s + i * 4) = val;
    }
    __syncthreads();

    // ---- ph2: h2[r][c] = mean_j relu(conv3_j(f1_synth)) ----
    for (int i = t; i < 34 * 32; i += 256) {
        int r = i >> 5;
        int c = i & 31;
        int v = vbase - 1 + r;
        float res = 0.0f;
        if (v >= 0 && v < V) {
            float u0 = w1[c * 3 + 0], u1 = w1[c * 3 + 1], u2 = w1[c * 3 + 2];
            float bc = b1[c];
            float w0 = wv2[0], w1_ = wv2[1], w2_ = wv2[2], b = bv2[0];
            const float* base = h3s + r * 32 * 4;
            float4 hh = *(const float4*)(base);
            float xprev = 0.0f;
            float xcur = fmaf(hh.x, u0, fmaf(hh.y, u1, fmaf(hh.z, u2, bc)));
            float s = 0.0f;
            #pragma unroll
            for (int j = 0; j < 32; ++j) {
                float xnext = 0.0f;
                if (j < 31) {
                    float4 hn = *(const float4*)(base + (j + 1) * 4);
                    xnext = fmaf(hn.x, u0, fmaf(hn.y, u1, fmaf(hn.z, u2, bc)));
                }
                float cv = fmaf(w0, xprev, fmaf(w1_, xcur, fmaf(w2_, xnext, b)));
                s += fmaxf(cv, 0.0f);
                xprev = xcur;
                xcur = xnext;
            }
            res = s * (1.0f / 32.0f);
        }
        h2s[r * 32 + c] = res;
    }
    __syncthreads();

    // ---- ph3: kD einsum from h2s -> f2s[32][68] (LDS) ----
    {
        int o = t & 63;
        int w = t >> 6;
        int vb = w * 8;
        float bo = b2[o];
        float acc[8];
        #pragma unroll
        for (int m = 0; m < 8; ++m) acc[m] = bo;

        #pragma unroll
        for (int c4 = 0; c4 < 8; ++c4) {
            float4 hv[10];
            #pragma unroll
            for (int r = 0; r < 10; ++r)
                hv[r] = *(const float4*)(h2s + (vb + r) * 32 + c4 * 4);
            #pragma unroll
            for (int k = 0; k < 3; ++k) {
                #pragma unroll
                for (int cc = 0; cc < 4; ++cc) {
                    int c = c4 * 4 + cc;
                    float wv = w2t[(k * 32 + c) * 64 + o];
                    #pragma unroll
                    for (int m = 0; m < 8; ++m) {
                        float hval = (cc == 0) ? hv[m + k].x :
                                     (cc == 1) ? hv[m + k].y :
                                     (cc == 2) ? hv[m + k].z : hv[m + k].w;
                        acc[m] = fmaf(hval, wv, acc[m]);
                    }
                }
            }
        }
        __syncthreads();   // h3s reads (ph2) done everywhere; safe to alias
        #pragma unroll
        for (int m = 0; m < 8; ++m)
            f2s[(vb + m) * 68 + o] = acc[m];
    }
    __syncthreads();

    // ---- ph4: kE MFMA fc + softmax (one pass, two row-sets) ----
    int w = t >> 6;          // wave 0..3
    int l = t & 63;          // lane
    int c16 = l & 15;
    int g = l >> 4;          // K-group / row-group

    bf16x8 ah0[2], am0[2], al0[2], ah1[2], am1[2], al1[2];
#define SPLIT(AH, AM, AL, idx, x) { \
        float xx = (x); \
        unsigned short h_ = f2bf(xx); \
        float r1_ = xx - bf2f(h_); \
        unsigned short m_ = f2bf(r1_); \
        float r2_ = r1_ - bf2f(m_); \
        AH[idx] = (short)h_; AM[idx] = (short)m_; AL[idx] = (short)f2bf(r2_); }
    #pragma unroll
    for (int set = 0; set < 2; ++set) {
        const float* rowp = f2s + (set * 16 + c16) * 68 + g * 8;
        float4 q0 = *(const float4*)(rowp);        // s=0, k=g*8..+3
        float4 q1 = *(const float4*)(rowp + 4);    // s=0, k=g*8+4..+7
        float4 q2 = *(const float4*)(rowp + 32);   // s=1
        float4 q3 = *(const float4*)(rowp + 36);
        SPLIT(ah0[set], am0[set], al0[set], 0, q0.x)
        SPLIT(ah0[set], am0[set], al0[set], 1, q0.y)
        SPLIT(ah0[set], am0[set], al0[set], 2, q0.z)
        SPLIT(ah0[set], am0[set], al0[set], 3, q0.w)
        SPLIT(ah0[set], am0[set], al0[set], 4, q1.x)
        SPLIT(ah0[set], am0[set], al0[set], 5, q1.y)
        SPLIT(ah0[set], am0[set], al0[set], 6, q1.z)
        SPLIT(ah0[set], am0[set], al0[set], 7, q1.w)
        SPLIT(ah1[set], am1[set], al1[set], 0, q2.x)
        SPLIT(ah1[set], am1[set], al1[set], 1, q2.y)
        SPLIT(ah1[set], am1[set], al1[set], 2, q2.z)
        SPLIT(ah1[set], am1[set], al1[set], 3, q2.w)
        SPLIT(ah1[set], am1[set], al1[set], 4, q3.x)
        SPLIT(ah1[set], am1[set], al1[set], 5, q3.y)
        SPLIT(ah1[set], am1[set], al1[set], 6, q3.z)
        SPLIT(ah1[set], am1[set], al1[set], 7, q3.w)
    }
#undef SPLIT

    f32x4 accA[8], accB[8];
    const bf16x8* Bh = (const bf16x8*)wBh;
    const bf16x8* Bm = (const bf16x8*)wBm;
    const bf16x8* Bl = (const bf16x8*)wBl;
    #pragma unroll
    for (int n8 = 0; n8 < 8; ++n8) {
        int n = w * 8 + n8;
        bf16x8 bh0 = Bh[(n * 2 + 0) * 64 + l];
        bf16x8 bm0 = Bm[(n * 2 + 0) * 64 + l];
        bf16x8 bl0 = Bl[(n * 2 + 0) * 64 + l];
        bf16x8 bh1 = Bh[(n * 2 + 1) * 64 + l];
        bf16x8 bm1 = Bm[(n * 2 + 1) * 64 + l];
        bf16x8 bl1 = Bl[(n * 2 + 1) * 64 + l];
        float bn = bfc[n * 16 + c16];
        f32x4 cA = {0.f, 0.f, 0.f, 0.f};
        cA = __builtin_amdgcn_mfma_f32_16x16x32_bf16(ah0[0], bh0, cA, 0, 0, 0);
        cA = __builtin_amdgcn_mfma_f32_16x16x32_bf16(ah0[0], bm0, cA, 0, 0, 0);
        cA = __builtin_amdgcn_mfma_f32_16x16x32_bf16(am0[0], bh0, cA, 0, 0, 0);
        cA = __builtin_amdgcn_mfma_f32_16x16x32_bf16(ah0[0], bl0, cA, 0, 0, 0);
        cA = __builtin_amdgcn_mfma_f32_16x16x32_bf16(am0[0], bm0, cA, 0, 0, 0);
        cA = __builtin_amdgcn_mfma_f32_16x16x32_bf16(al0[0], bh0, cA, 0, 0, 0);
        cA = __builtin_amdgcn_mfma_f32_16x16x32_bf16(ah1[0], bh1, cA, 0, 0, 0);
        cA = __builtin_amdgcn_mfma_f32_16x16x32_bf16(ah1[0], bm1, cA, 0, 0, 0);
        cA = __builtin_amdgcn_mfma_f32_16x16x32_bf16(am1[0], bh1, cA, 0, 0, 0);
        cA = __builtin_amdgcn_mfma_f32_16x16x32_bf16(ah1[0], bl1, cA, 0, 0, 0);
        cA = __builtin_amdgcn_mfma_f32_16x16x32_bf16(am1[0], bm1, cA, 0, 0, 0);
        cA = __builtin_amdgcn_mfma_f32_16x16x32_bf16(al1[0], bh1, cA, 0, 0, 0);
        cA.x += bn; cA.y += bn; cA.z += bn; cA.w += bn;
        accA[n8] = cA;
        f32x4 cB = {0.f, 0.f, 0.f, 0.f};
        cB = __builtin_amdgcn_mfma_f32_16x16x32_bf16(ah0[1], bh0, cB, 0, 0, 0);
        cB = __builtin_amdgcn_mfma_f32_16x16x32_bf16(ah0[1], bm0, cB, 0, 0, 0);
        cB = __builtin_amdgcn_mfma_f32_16x16x32_bf16(am0[1], bh0, cB, 0, 0, 0);
        cB = __builtin_amdgcn_mfma_f32_16x16x32_bf16(ah0[1], bl0, cB, 0, 0, 0);
        cB = __builtin_amdgcn_mfma_f32_16x16x32_bf16(am0[1], bm0, cB, 0, 0, 0);
        cB = __builtin_amdgcn_mfma_f32_16x16x32_bf16(al0[1], bh0, cB, 0, 0, 0);
        cB = __builtin_amdgcn_mfma_f32_16x16x32_bf16(ah1[1], bh1, cB, 0, 0, 0);
        cB = __builtin_amdgcn_mfma_f32_16x16x32_bf16(ah1[1], bm1, cB, 0, 0, 0);
        cB = __builtin_amdgcn_mfma_f32_16x16x32_bf16(am1[1], bh1, cB, 0, 0, 0);
        cB = __builtin_amdgcn_mfma_f32_16x16x32_bf16(ah1[1], bl1, cB, 0, 0, 0);
        cB = __builtin_amdgcn_mfma_f32_16x16x32_bf16(am1[1], bm1, cB, 0, 0, 0);
        cB = __builtin_amdgcn_mfma_f32_16x16x32_bf16(al1[1], bh1, cB, 0, 0, 0);
        cB.x += bn; cB.y += bn; cB.z += bn; cB.w += bn;
        accB[n8] = cB;
    }

    // ---- softmax: per reg j, set s: row = s*16 + g*4 + j ----
    float mA0 = -1e30f, mA1 = -1e30f, mA2 = -1e30f, mA3 = -1e30f;
    float mB0 = -1e30f, mB1 = -1e30f, mB2 = -1e30f, mB3 = -1e30f;
    #pragma unroll
    for (int n8 = 0; n8 < 8; ++n8) {
        mA0 = fmaxf(mA0, accA[n8].x); mA1 = fmaxf(mA1, accA[n8].y);
        mA2 = fmaxf(mA2, accA[n8].z); mA3 = fmaxf(mA3, accA[n8].w);
        mB0 = fmaxf(mB0, accB[n8].x); mB1 = fmaxf(mB1, accB[n8].y);
        mB2 = fmaxf(mB2, accB[n8].z); mB3 = fmaxf(mB3, accB[n8].w);
    }
    #pragma unroll
    for (int off = 8; off; off >>= 1) {
        mA0 = fmaxf(mA0, __shfl_xor(mA0, off));
        mA1 = fmaxf(mA1, __shfl_xor(mA1, off));
        mA2 = fmaxf(mA2, __shfl_xor(mA2, off));
        mA3 = fmaxf(mA3, __shfl_xor(mA3, off));
        mB0 = fmaxf(mB0, __shfl_xor(mB0, off));
        mB1 = fmaxf(mB1, __shfl_xor(mB1, off));
        mB2 = fmaxf(mB2, __shfl_xor(mB2, off));
        mB3 = fmaxf(mB3, __shfl_xor(mB3, off));
    }
    if (c16 == 0) {
        redmax[w][g * 4 + 0] = mA0;  redmax[w][g * 4 + 1] = mA1;
        redmax[w][g * 4 + 2] = mA2;  redmax[w][g * 4 + 3] = mA3;
        redmax[w][16 + g * 4 + 0] = mB0;  redmax[w][16 + g * 4 + 1] = mB1;
        redmax[w][16 + g * 4 + 2] = mB2;  redmax[w][16 + g * 4 + 3] = mB3;
    }
    __syncthreads();
#define GMAX(r) fmaxf(fmaxf(redmax[0][r], redmax[1][r]), \
                      fmaxf(redmax[2][r], redmax[3][r]))
    float gA0 = GMAX(g * 4 + 0), gA1 = GMAX(g * 4 + 1);
    float gA2 = GMAX(g * 4 + 2), gA3 = GMAX(g * 4 + 3);
    float gB0 = GMAX(16 + g * 4 + 0), gB1 = GMAX(16 + g * 4 + 1);
    float gB2 = GMAX(16 + g * 4 + 2), gB3 = GMAX(16 + g * 4 + 3);
#undef GMAX

    float sA0 = 0.f, sA1 = 0.f, sA2 = 0.f, sA3 = 0.f;
    float sB0 = 0.f, sB1 = 0.f, sB2 = 0.f, sB3 = 0.f;
    #pragma unroll
    for (int n8 = 0; n8 < 8; ++n8) {
        accA[n8].x = __expf(accA[n8].x - gA0); sA0 += accA[n8].x;
        accA[n8].y = __expf(accA[n8].y - gA1); sA1 += accA[n8].y;
        accA[n8].z = __expf(accA[n8].z - gA2); sA2 += accA[n8].z;
        accA[n8].w = __expf(accA[n8].w - gA3); sA3 += accA[n8].w;
        accB[n8].x = __expf(accB[n8].x - gB0); sB0 += accB[n8].x;
        accB[n8].y = __expf(accB[n8].y - gB1); sB1 += accB[n8].y;
        accB[n8].z = __expf(accB[n8].z - gB2); sB2 += accB[n8].z;
        accB[n8].w = __expf(accB[n8].w - gB3); sB3 += accB[n8].w;
    }
    #pragma unroll
    for (int off = 8; off; off >>= 1) {
        sA0 += __shfl_xor(sA0, off); sA1 += __shfl_xor(sA1, off);
        sA2 += __shfl_xor(sA2, off); sA3 += __shfl_xor(sA3, off);
        sB0 += __shfl_xor(sB0, off); sB1 += __shfl_xor(sB1, off);
        sB2 += __shfl_xor(sB2, off); sB3 += __shfl_xor(sB3, off);
    }
    if (c16 == 0) {
        redsum[w][g * 4 + 0] = sA0;  redsum[w][g * 4 + 1] = sA1;
        redsum[w][g * 4 + 2] = sA2;  redsum[w][g * 4 + 3] = sA3;
        redsum[w][16 + g * 4 + 0] = sB0;  redsum[w][16 + g * 4 + 1] = sB1;
        redsum[w][16 + g * 4 + 2] = sB2;  redsum[w][16 + g * 4 + 3] = sB3;
    }
    __syncthreads();
#define GSUM(r) (redsum[0][r] + redsum[1][r] + redsum[2][r] + redsum[3][r])
    float iA0 = 1.0f / GSUM(g * 4 + 0), iA1 = 1.0f / GSUM(g * 4 + 1);
    float iA2 = 1.0f / GSUM(g * 4 + 2), iA3 = 1.0f / GSUM(g * 4 + 3);
    float iB0 = 1.0f / GSUM(16 + g * 4 + 0), iB1 = 1.0f / GSUM(16 + g * 4 + 1);
    float iB2 = 1.0f / GSUM(16 + g * 4 + 2), iB3 = 1.0f / GSUM(16 + g * 4 + 3);
#undef GSUM

    #pragma unroll
    for (int n8 = 0; n8 < 8; ++n8) {
        int n = w * 8 + n8;
        float* opA = out + (size_t)(vbase + g * 4) * 512 + n * 16 + c16;
        __builtin_nontemporal_store(accA[n8].x * iA0, opA);
        __builtin_nontemporal_store(accA[n8].y * iA1, opA + 512);
        __builtin_nontemporal_store(accA[n8].z * iA2, opA + 1024);
        __builtin_nontemporal_store(accA[n8].w * iA3, opA + 1536);
        float* opB = opA + 16 * 512;
        __builtin_nontemporal_store(accB[n8].x * iB0, opB);
        __builtin_nontemporal_store(accB[n8].y * iB1, opB + 512);
        __builtin_nontemporal_store(accB[n8].z * iB2, opB + 1024);
        __builtin_nontemporal_store(accB[n8].w * iB3, opB + 1536);
    }
}

extern "C" void kernel_launch(void* const* d_in, const int* in_sizes, int n_in,
                              void* d_out, int out_size, void* d_ws, size_t ws_size,
                              hipStream_t stream) {
    (void)n_in; (void)out_size; (void)ws_size;
    const float* vp  = (const float*)d_in[0];
    const int*   nb1 = (const int*)d_in[1];
    const int*   nb2 = (const int*)d_in[2];
    const float* wv1 = (const float*)d_in[3];
    const float* bv1 = (const float*)d_in[4];
    const float* w1  = (const float*)d_in[5];
    const float* b1  = (const float*)d_in[6];
    const float* wv2 = (const float*)d_in[7];
    const float* bv2 = (const float*)d_in[8];
    const float* w2  = (const float*)d_in[9];
    const float* b2  = (const float*)d_in[10];
    const float* wfc = (const float*)d_in[11];
    const float* bfc = (const float*)d_in[12];
    float* out = (float*)d_out;
    const int V = in_sizes[0];

    float* ws = (float*)d_ws;
    size_t off = 0;
    float* h    = ws + off; off += (size_t)V;
    float* h3   = ws + off; off += (size_t)V * 4;   // 16B aligned
    float* w2t  = ws + off; off += 3 * 32 * 64;
    short* wBh  = (short*)(ws + off); off += 32768 / 2;   // 32768 shorts
    short* wBm  = (short*)(ws + off); off += 32768 / 2;
    short* wBl  = (short*)(ws + off); off += 32768 / 2;

    k_prep<<<(32768 + 6144 + 255) / 256, 256, 0, stream>>>(wfc, w2, wBh, wBm, wBl, w2t);
    kA<<<(V * 32 + 255) / 256, 256, 0, stream>>>(vp, nb1, wv1, bv1, h, V);
    kB<<<(V + 255) / 256, 256, 0, stream>>>(h, h3, V);
    kF<<<V / 32, 256, 0, stream>>>(h3, nb2, w1, b1, wv2, bv2, w2t, b2,
                                   wBh, wBm, wBl, bfc, out, V);
}

// Round 16
// 362.348 us; speedup vs baseline: 1.5345x; 1.1319x over previous
//
#include <hip/hip_runtime.h>

// ---------------------------------------------------------------------------
// Pipeline:
//  k_prep : w2[64,32,3] -> w2t[3,32,64]; wfc[512,64] -> wB{h,m,l} bf16
//  kA     : h[v] = mean_j relu(conv3_j(vp[nb1[v,:]]))               [V]
//  kB     : h3[v] = (h[v-1], h[v], h[v+1], 0)                       [V,4]
//  kF     : FUSED kC+kD+kE per 32-vertex block, 512 THREADS / 8 WAVES
//
// R19: ph4 live-state reduction done in PARALLEL, not serial.
// Ledger: R12 one-pass/bare: 96 VGPR, +75MB spill, kF 178us (best, 386.5).
//         R13/R14/R15: launch-bounds attempts -> 64/156/84 VGPR, all worse.
// The RA heuristic is not steerable via launch_bounds; the structural fix
// is fewer live floats per thread. 512-thr blocks: 8 waves, each wave owns
// ONE row-set x 8 N-tiles -> 6 A-frags (24 VGPR) + acc[8] (32) + temps
// ~= 70 live. Fits any plausible allocation -> no scratch. ph1/ph2 restrided;
// ph3 = 8 waves x 4 rows. Same math chains -> absmax must stay 1.525879e-05.
// Verify: WRITE -> ~205MB (spill gone), occ -> 50%+, kF -> ~110-140us.
// ---------------------------------------------------------------------------

typedef short bf16x8 __attribute__((ext_vector_type(8)));
typedef float f32x4 __attribute__((ext_vector_type(4)));

__device__ inline unsigned short f2bf(float x) {
    unsigned u = __float_as_uint(x);
    unsigned r = (u + 0x7FFFu + ((u >> 16) & 1u)) >> 16;
    return (unsigned short)r;
}
__device__ inline float bf2f(unsigned short b) {
    return __uint_as_float(((unsigned)b) << 16);
}

// k_prep: w2 transpose + wfc -> 3-way bf16 split in B-fragment order.
__global__ __launch_bounds__(256) void k_prep(const float* __restrict__ wfc,
                                              const float* __restrict__ w2,
                                              short* __restrict__ wBh,
                                              short* __restrict__ wBm,
                                              short* __restrict__ wBl,
                                              float* __restrict__ w2t) {
    int t = blockIdx.x * 256 + threadIdx.x;
    if (t < 32768) {
        int j = t & 7;
        int l = (t >> 3) & 63;
        int s = (t >> 9) & 1;
        int n = t >> 10;
        int col = n * 16 + (l & 15);
        int k = s * 32 + (l >> 4) * 8 + j;
        float v = wfc[col * 64 + k];
        unsigned short h = f2bf(v);
        float r1 = v - bf2f(h);
        unsigned short m = f2bf(r1);
        float r2 = r1 - bf2f(m);
        wBh[t] = (short)h;
        wBm[t] = (short)m;
        wBl[t] = (short)f2bf(r2);
    } else if (t < 32768 + 6144) {
        int i = t - 32768;
        int o = i / 96;
        int r = i - o * 96;
        int c = r / 3;
        int k = r - c * 3;
        w2t[(k * 32 + c) * 64 + o] = w2[i];
    }
}

// conv1 over neighbor axis: one 32-lane segment per vertex
__global__ __launch_bounds__(256) void kA(const float* __restrict__ vp,
                                          const int* __restrict__ nb1,
                                          const float* __restrict__ wv1,
                                          const float* __restrict__ bv1,
                                          float* __restrict__ h, int V) {
    int t = blockIdx.x * 256 + threadIdx.x;
    int v = t >> 5;
    int j = t & 31;
    if (v >= V) return;
    float g = vp[nb1[v * 32 + j]];
    float gm = __shfl_up(g, 1, 32);
    if (j == 0) gm = 0.0f;
    float gp = __shfl_down(g, 1, 32);
    if (j == 31) gp = 0.0f;
    float c = wv1[0] * gm + wv1[1] * g + wv1[2] * gp + bv1[0];
    c = fmaxf(c, 0.0f);
    #pragma unroll
    for (int off = 16; off; off >>= 1) c += __shfl_xor(c, off, 32);
    if (j == 0) h[v] = c * (1.0f / 32.0f);
}

// h3 builder: h3[v] = (h[v-1], h[v], h[v+1], 0) -- 1.6MB, L2-resident
__global__ __launch_bounds__(256) void kB(const float* __restrict__ h,
                                          float* __restrict__ h3, int V) {
    int v = blockIdx.x * 256 + threadIdx.x;
    if (v >= V) return;
    float hm = (v > 0) ? h[v - 1] : 0.0f;
    float h0 = h[v];
    float hp = (v + 1 < V) ? h[v + 1] : 0.0f;
    *(float4*)(h3 + (size_t)v * 4) = make_float4(hm, h0, hp, 0.0f);
}

// FUSED kC+kD+kE. One block = 32 vertices, 512 threads / 8 waves.
__global__ __launch_bounds__(512) void kF(const float* __restrict__ h3,
                                          const int* __restrict__ nb2,
                                          const float* __restrict__ w1,
                                          const float* __restrict__ b1,
                                          const float* __restrict__ wv2,
                                          const float* __restrict__ bv2,
                                          const float* __restrict__ w2t,
                                          const float* __restrict__ b2,
                                          const short* __restrict__ wBh,
                                          const short* __restrict__ wBm,
                                          const short* __restrict__ wBl,
                                          const float* __restrict__ bfc,
                                          float* __restrict__ out, int V) {
    __shared__ float h3s[34 * 32 * 4];   // 17408 B; ph3+ aliased as f2s[32][68]
    __shared__ float h2s[34 * 32];       // 4352 B, rows v0-1 .. v0+32
    __shared__ float redmax[8][16];
    __shared__ float redsum[8][16];
    float* f2s = h3s;                    // alias (dead after ph2; barrier-fenced)

    int t = threadIdx.x;
    int vbase = blockIdx.x * 32;

    // ---- ph1: gather h3[nb2[v,j]] for 34 halo rows ----
    for (int i = t; i < 34 * 32; i += 512) {
        int r = i >> 5;                  // tile row, vertex v = vbase-1+r
        int j = i & 31;
        int v = vbase - 1 + r;
        float4 val = make_float4(0.f, 0.f, 0.f, 0.f);
        if (v >= 0 && v < V) {
            int idx = nb2[(size_t)v * 32 + j];
            val = *(const float4*)(h3 + (size_t)idx * 4);
        }
        *(float4*)(h3s + i * 4) = val;
    }
    __syncthreads();

    // ---- ph2: h2[r][c] = mean_j relu(conv3_j(f1_synth)) ----
    for (int i = t; i < 34 * 32; i += 512) {
        int r = i >> 5;
        int c = i & 31;
        int v = vbase - 1 + r;
        float res = 0.0f;
        if (v >= 0 && v < V) {
            float u0 = w1[c * 3 + 0], u1 = w1[c * 3 + 1], u2 = w1[c * 3 + 2];
            float bc = b1[c];
            float w0 = wv2[0], w1_ = wv2[1], w2_ = wv2[2], b = bv2[0];
            const float* base = h3s + r * 32 * 4;
            float4 hh = *(const float4*)(base);
            float xprev = 0.0f;
            float xcur = fmaf(hh.x, u0, fmaf(hh.y, u1, fmaf(hh.z, u2, bc)));
            float s = 0.0f;
            #pragma unroll
            for (int j = 0; j < 32; ++j) {
                float xnext = 0.0f;
                if (j < 31) {
                    float4 hn = *(const float4*)(base + (j + 1) * 4);
                    xnext = fmaf(hn.x, u0, fmaf(hn.y, u1, fmaf(hn.z, u2, bc)));
                }
                float cv = fmaf(w0, xprev, fmaf(w1_, xcur, fmaf(w2_, xnext, b)));
                s += fmaxf(cv, 0.0f);
                xprev = xcur;
                xcur = xnext;
            }
            res = s * (1.0f / 32.0f);
        }
        h2s[r * 32 + c] = res;
    }
    __syncthreads();

    // ---- ph3: kD einsum from h2s -> f2s[32][68] (LDS); 8 waves x 4 rows --
    {
        int o = t & 63;
        int w8 = t >> 6;      // 0..7
        int vb = w8 * 4;
        float bo = b2[o];
        float acc[4];
        #pragma unroll
        for (int m = 0; m < 4; ++m) acc[m] = bo;

        #pragma unroll
        for (int c4 = 0; c4 < 8; ++c4) {
            float4 hv[6];
            #pragma unroll
            for (int r = 0; r < 6; ++r)
                hv[r] = *(const float4*)(h2s + (vb + r) * 32 + c4 * 4);
            #pragma unroll
            for (int k = 0; k < 3; ++k) {
                #pragma unroll
                for (int cc = 0; cc < 4; ++cc) {
                    int c = c4 * 4 + cc;
                    float wv = w2t[(k * 32 + c) * 64 + o];
                    #pragma unroll
                    for (int m = 0; m < 4; ++m) {
                        float hval = (cc == 0) ? hv[m + k].x :
                                     (cc == 1) ? hv[m + k].y :
                                     (cc == 2) ? hv[m + k].z : hv[m + k].w;
                        acc[m] = fmaf(hval, wv, acc[m]);
                    }
                }
            }
        }
        __syncthreads();   // all h3s reads (ph2) complete; safe to alias
        #pragma unroll
        for (int m = 0; m < 4; ++m)
            f2s[(vb + m) * 68 + o] = acc[m];
    }
    __syncthreads();

    // ---- ph4: kE MFMA fc + softmax; wave w8 owns row-set (w8>>2),
    //      N-tiles (w8&3)*8 .. +7. Live state ~70 floats/thread. ----
    int w8 = t >> 6;         // 0..7
    int set = w8 >> 2;       // row-set 0..1
    int wq = w8 & 3;         // N-quadrant 0..3
    int l = t & 63;
    int c16 = l & 15;
    int g = l >> 4;          // K-group / row-group

    bf16x8 ah0, am0, al0, ah1, am1, al1;
#define SPLIT(AH, AM, AL, idx, x) { \
        float xx = (x); \
        unsigned short h_ = f2bf(xx); \
        float r1_ = xx - bf2f(h_); \
        unsigned short m_ = f2bf(r1_); \
        float r2_ = r1_ - bf2f(m_); \
        AH[idx] = (short)h_; AM[idx] = (short)m_; AL[idx] = (short)f2bf(r2_); }
    {
        const float* rowp = f2s + (set * 16 + c16) * 68 + g * 8;
        float4 q0 = *(const float4*)(rowp);        // s=0, k=g*8..+3
        float4 q1 = *(const float4*)(rowp + 4);    // s=0, k=g*8+4..+7
        float4 q2 = *(const float4*)(rowp + 32);   // s=1
        float4 q3 = *(const float4*)(rowp + 36);
        SPLIT(ah0, am0, al0, 0, q0.x) SPLIT(ah0, am0, al0, 1, q0.y)
        SPLIT(ah0, am0, al0, 2, q0.z) SPLIT(ah0, am0, al0, 3, q0.w)
        SPLIT(ah0, am0, al0, 4, q1.x) SPLIT(ah0, am0, al0, 5, q1.y)
        SPLIT(ah0, am0, al0, 6, q1.z) SPLIT(ah0, am0, al0, 7, q1.w)
        SPLIT(ah1, am1, al1, 0, q2.x) SPLIT(ah1, am1, al1, 1, q2.y)
        SPLIT(ah1, am1, al1, 2, q2.z) SPLIT(ah1, am1, al1, 3, q2.w)
        SPLIT(ah1, am1, al1, 4, q3.x) SPLIT(ah1, am1, al1, 5, q3.y)
        SPLIT(ah1, am1, al1, 6, q3.z) SPLIT(ah1, am1, al1, 7, q3.w)
    }
#undef SPLIT

    f32x4 acc[8];
    const bf16x8* Bh = (const bf16x8*)wBh;
    const bf16x8* Bm = (const bf16x8*)wBm;
    const bf16x8* Bl = (const bf16x8*)wBl;
    #pragma unroll
    for (int n8 = 0; n8 < 8; ++n8) {
        int n = wq * 8 + n8;
        bf16x8 bh0 = Bh[(n * 2 + 0) * 64 + l];
        bf16x8 bm0 = Bm[(n * 2 + 0) * 64 + l];
        bf16x8 bl0 = Bl[(n * 2 + 0) * 64 + l];
        bf16x8 bh1 = Bh[(n * 2 + 1) * 64 + l];
        bf16x8 bm1 = Bm[(n * 2 + 1) * 64 + l];
        bf16x8 bl1 = Bl[(n * 2 + 1) * 64 + l];
        float bn = bfc[n * 16 + c16];
        f32x4 c = {0.f, 0.f, 0.f, 0.f};
        c = __builtin_amdgcn_mfma_f32_16x16x32_bf16(ah0, bh0, c, 0, 0, 0);
        c = __builtin_amdgcn_mfma_f32_16x16x32_bf16(ah0, bm0, c, 0, 0, 0);
        c = __builtin_amdgcn_mfma_f32_16x16x32_bf16(am0, bh0, c, 0, 0, 0);
        c = __builtin_amdgcn_mfma_f32_16x16x32_bf16(ah0, bl0, c, 0, 0, 0);
        c = __builtin_amdgcn_mfma_f32_16x16x32_bf16(am0, bm0, c, 0, 0, 0);
        c = __builtin_amdgcn_mfma_f32_16x16x32_bf16(al0, bh0, c, 0, 0, 0);
        c = __builtin_amdgcn_mfma_f32_16x16x32_bf16(ah1, bh1, c, 0, 0, 0);
        c = __builtin_amdgcn_mfma_f32_16x16x32_bf16(ah1, bm1, c, 0, 0, 0);
        c = __builtin_amdgcn_mfma_f32_16x16x32_bf16(am1, bh1, c, 0, 0, 0);
        c = __builtin_amdgcn_mfma_f32_16x16x32_bf16(ah1, bl1, c, 0, 0, 0);
        c = __builtin_amdgcn_mfma_f32_16x16x32_bf16(am1, bm1, c, 0, 0, 0);
        c = __builtin_amdgcn_mfma_f32_16x16x32_bf16(al1, bh1, c, 0, 0, 0);
        c.x += bn; c.y += bn; c.z += bn; c.w += bn;
        acc[n8] = c;
    }

    // ---- softmax: rows set*16 + g*4 + j; 16-lane reduce then 4-wave
    //      combine (waves set*4 .. set*4+3) via LDS ----
    float m0 = -1e30f, m1 = -1e30f, m2 = -1e30f, m3 = -1e30f;
    #pragma unroll
    for (int n8 = 0; n8 < 8; ++n8) {
        m0 = fmaxf(m0, acc[n8].x); m1 = fmaxf(m1, acc[n8].y);
        m2 = fmaxf(m2, acc[n8].z); m3 = fmaxf(m3, acc[n8].w);
    }
    #pragma unroll
    for (int off = 8; off; off >>= 1) {
        m0 = fmaxf(m0, __shfl_xor(m0, off));
        m1 = fmaxf(m1, __shfl_xor(m1, off));
        m2 = fmaxf(m2, __shfl_xor(m2, off));
        m3 = fmaxf(m3, __shfl_xor(m3, off));
    }
    if (c16 == 0) {
        redmax[w8][g * 4 + 0] = m0;  redmax[w8][g * 4 + 1] = m1;
        redmax[w8][g * 4 + 2] = m2;  redmax[w8][g * 4 + 3] = m3;
    }
    __syncthreads();
#define GMAX(r) fmaxf(fmaxf(redmax[set * 4 + 0][r], redmax[set * 4 + 1][r]), \
                      fmaxf(redmax[set * 4 + 2][r], redmax[set * 4 + 3][r]))
    float g0 = GMAX(g * 4 + 0), g1 = GMAX(g * 4 + 1);
    float g2 = GMAX(g * 4 + 2), g3 = GMAX(g * 4 + 3);
#undef GMAX

    float s0 = 0.f, s1 = 0.f, s2 = 0.f, s3 = 0.f;
    #pragma unroll
    for (int n8 = 0; n8 < 8; ++n8) {
        acc[n8].x = __expf(acc[n8].x - g0); s0 += acc[n8].x;
        acc[n8].y = __expf(acc[n8].y - g1); s1 += acc[n8].y;
        acc[n8].z = __expf(acc[n8].z - g2); s2 += acc[n8].z;
        acc[n8].w = __expf(acc[n8].w - g3); s3 += acc[n8].w;
    }
    #pragma unroll
    for (int off = 8; off; off >>= 1) {
        s0 += __shfl_xor(s0, off); s1 += __shfl_xor(s1, off);
        s2 += __shfl_xor(s2, off); s3 += __shfl_xor(s3, off);
    }
    if (c16 == 0) {
        redsum[w8][g * 4 + 0] = s0;  redsum[w8][g * 4 + 1] = s1;
        redsum[w8][g * 4 + 2] = s2;  redsum[w8][g * 4 + 3] = s3;
    }
    __syncthreads();
#define GSUM(r) (redsum[set * 4 + 0][r] + redsum[set * 4 + 1][r] + \
                 redsum[set * 4 + 2][r] + redsum[set * 4 + 3][r])
    float i0 = 1.0f / GSUM(g * 4 + 0), i1 = 1.0f / GSUM(g * 4 + 1);
    float i2 = 1.0f / GSUM(g * 4 + 2), i3 = 1.0f / GSUM(g * 4 + 3);
#undef GSUM

    // ---- store: out[(vbase+set*16+g*4+j)*512 + n*16 + c16] ----
    #pragma unroll
    for (int n8 = 0; n8 < 8; ++n8) {
        int n = wq * 8 + n8;
        float* op = out + (size_t)(vbase + set * 16 + g * 4) * 512 + n * 16 + c16;
        __builtin_nontemporal_store(acc[n8].x * i0, op);
        __builtin_nontemporal_store(acc[n8].y * i1, op + 512);
        __builtin_nontemporal_store(acc[n8].z * i2, op + 1024);
        __builtin_nontemporal_store(acc[n8].w * i3, op + 1536);
    }
}

extern "C" void kernel_launch(void* const* d_in, const int* in_sizes, int n_in,
                              void* d_out, int out_size, void* d_ws, size_t ws_size,
                              hipStream_t stream) {
    (void)n_in; (void)out_size; (void)ws_size;
    const float* vp  = (const float*)d_in[0];
    const int*   nb1 = (const int*)d_in[1];
    const int*   nb2 = (const int*)d_in[2];
    const float* wv1 = (const float*)d_in[3];
    const float* bv1 = (const float*)d_in[4];
    const float* w1  = (const float*)d_in[5];
    const float* b1  = (const float*)d_in[6];
    const float* wv2 = (const float*)d_in[7];
    const float* bv2 = (const float*)d_in[8];
    const float* w2  = (const float*)d_in[9];
    const float* b2  = (const float*)d_in[10];
    const float* wfc = (const float*)d_in[11];
    const float* bfc = (const float*)d_in[12];
    float* out = (float*)d_out;
    const int V = in_sizes[0];

    float* ws = (float*)d_ws;
    size_t off = 0;
    float* h    = ws + off; off += (size_t)V;
    float* h3   = ws + off; off += (size_t)V * 4;   // 16B aligned
    float* w2t  = ws + off; off += 3 * 32 * 64;
    short* wBh  = (short*)(ws + off); off += 32768 / 2;   // 32768 shorts
    short* wBm  = (short*)(ws + off); off += 32768 / 2;
    short* wBl  = (short*)(ws + off); off += 32768 / 2;

    k_prep<<<(32768 + 6144 + 255) / 256, 256, 0, stream>>>(wfc, w2, wBh, wBm, wBl, w2t);
    kA<<<(V * 32 + 255) / 256, 256, 0, stream>>>(vp, nb1, wv1, bv1, h, V);
    kB<<<(V + 255) / 256, 256, 0, stream>>>(h, h3, V);
    kF<<<V / 32, 512, 0, stream>>>(h3, nb2, w1, b1, wv2, bv2, w2t, b2,
                                   wBh, wBm, wBl, bfc, out, V);
}